// Round 5
// baseline (1735.798 us; speedup 1.0000x reference)
//
#include <hip/hip_runtime.h>

typedef unsigned short u16;
using bf8   = __attribute__((ext_vector_type(8))) short;  // 8 bf16 (4 VGPRs)
using bf4   = __attribute__((ext_vector_type(4))) short;  // 4 bf16
using f32x4 = __attribute__((ext_vector_type(4))) float;

#define B_ 256
#define T_ 512
#define D_ 64
#define H_ 256
#define Tc_ 64
#define NC_ (T_ / Tc_)
#define GEMMB_ 190   // gemm blocks; 190*16 = 3040 waves = 152 j-slots * 20 units

#define MFMA(a, b, c) __builtin_amdgcn_mfma_f32_16x16x32_bf16(a, b, c, 0, 0, 0)

static __device__ inline u16 f2b(float f) {
    unsigned int u = __float_as_uint(f);
    unsigned int r = (u + 0x7fffu + ((u >> 16) & 1u)) >> 16;
    return (u16)r;
}
static __device__ inline float fast_tanh(float x) {
    float e = __expf(2.f * x);
    return 1.f - 2.f / (e + 1.f);
}
static __device__ inline float fast_sigmoid(float x) {
    return 1.f / (1.f + __expf(-x));
}
// Raw barrier: waits LDS ops only, leaves global prefetch loads/stores in
// flight (avoids __syncthreads' compiler-emitted vmcnt(0) drain).
static __device__ inline void lds_barrier() {
    asm volatile("s_waitcnt lgkmcnt(0)" ::: "memory");
    __builtin_amdgcn_s_barrier();
    asm volatile("" ::: "memory");
}

// ---------------------------------------------------------------------------
// k_conv: f32 -> bf16 weight conversion pre-pass.
// ---------------------------------------------------------------------------
__global__ __launch_bounds__(256) void k_conv(
    const float* __restrict__ W1w, const float* __restrict__ U1w,
    const float* __restrict__ W2w, const float* __restrict__ U2w,
    const float* __restrict__ o1w, const float* __restrict__ o2w,
    const float* __restrict__ gw,
    u16* W1bf, u16* U1bf, u16* W2bf, u16* U2bf,
    u16* o1bf, u16* o2bf, u16* gbf)
{
    const int a = blockIdx.y;
    const float* src; u16* dst; int n;
    switch (a) {
        case 0: src = W1w; dst = W1bf; n = 16384;  break;
        case 1: src = U1w; dst = U1bf; n = 65536;  break;
        case 2: src = W2w; dst = W2bf; n = 65536;  break;
        case 3: src = U2w; dst = U2bf; n = 65536;  break;
        case 4: src = o1w; dst = o1bf; n = 16384;  break;
        case 5: src = o2w; dst = o2bf; n = 16384;  break;
        default: src = gw; dst = gbf;  n = 131072; break;
    }
    const int i = (blockIdx.x * 256 + threadIdx.x) * 4;
    if (i < n) {
        f32x4 v = *(const f32x4*)(src + i);
        bf4 o;
        o[0] = (short)f2b(v[0]); o[1] = (short)f2b(v[1]);
        o[2] = (short)f2b(v[2]); o[3] = (short)f2b(v[3]);
        *(bf4*)(dst + i) = o;
    }
}

// ---------------------------------------------------------------------------
// h1 role: blocks 0-15. Chunk c. 16 waves, ONE n-chain each (16 cols).
// Nominal VGPRs: u1f 32 + w1f 8 + haf 32 + xa 16 + xaf 8 + acc 4 + misc ~11
// = ~111 <= 128 budget -> zero weight remat. x loaded at step top (L3-
// resident, ~280 cy cover to its use after the U-chain).
// ---------------------------------------------------------------------------
__device__ void h1_role(
    const float* __restrict__ x, const u16* __restrict__ W1,
    const u16* __restrict__ U1, const float* __restrict__ W1b,
    const float* __restrict__ U1b, u16* __restrict__ H1,
    u16* __restrict__ h1state, int c, u16 (*buf)[16][H_ + 8])
{
    const int g = blockIdx.x;
    const int tid = threadIdx.x;
    const int w = tid >> 6, lane = tid & 63;
    const int col = lane & 15, quad = lane >> 4;
    const int t0 = c * Tc_;
    const int n = w * 16 + col;

    bf8 u1f[8], w1f[2];
#pragma unroll
    for (int kt = 0; kt < 8; ++kt)
        u1f[kt] = *(const bf8*)(U1 + (size_t)n * H_ + kt * 32 + quad * 8);
#pragma unroll
    for (int kt = 0; kt < 2; ++kt)
        w1f[kt] = *(const bf8*)(W1 + (size_t)n * D_ + kt * 32 + quad * 8);
    const float bias = W1b[n] + U1b[n];

    if (c == 0) {
        for (int idx = tid; idx < 16 * (H_ + 8); idx += 1024)
            ((u16*)buf[0])[idx] = 0;
    } else {
        const int m = tid >> 6, hb = (tid & 63) * 4;
        *(bf4*)&buf[0][m][hb] =
            *(const bf4*)(h1state + (size_t)(g * 16 + m) * H_ + hb);
    }
    __syncthreads();

    const float* xrow = x + (size_t)(g * 16 + col) * T_ * D_ + quad * 8;

    int p = 0;
    for (int tt = 0; tt < Tc_; ++tt) {
        // x loads issued at step top; consumed after the U-chain (cover).
        const float* xp = xrow + (size_t)(t0 + tt) * D_;
        f32x4 xa0 = *(const f32x4*)xp;
        f32x4 xa1 = *(const f32x4*)(xp + 4);
        f32x4 xa2 = *(const f32x4*)(xp + 32);
        f32x4 xa3 = *(const f32x4*)(xp + 36);

        bf8 haf[8];
#pragma unroll
        for (int kt = 0; kt < 8; ++kt)
            haf[kt] = *(const bf8*)&buf[p][col][kt * 32 + quad * 8];

        f32x4 acc;
        acc[0] = bias; acc[1] = bias; acc[2] = bias; acc[3] = bias;
#pragma unroll
        for (int kt = 0; kt < 8; ++kt)
            acc = MFMA(haf[kt], u1f[kt], acc);

        bf8 xaf[2];
#pragma unroll
        for (int j = 0; j < 4; ++j) {
            xaf[0][j]     = (short)f2b(xa0[j]);
            xaf[0][j + 4] = (short)f2b(xa1[j]);
            xaf[1][j]     = (short)f2b(xa2[j]);
            xaf[1][j + 4] = (short)f2b(xa3[j]);
        }
#pragma unroll
        for (int kt = 0; kt < 2; ++kt)
            acc = MFMA(xaf[kt], w1f[kt], acc);

#pragma unroll
        for (int r = 0; r < 4; ++r)
            buf[p ^ 1][quad * 4 + r][n] = f2b(fast_tanh(acc[r]));
        lds_barrier();
        {
            const int m = tid >> 6, hb = (tid & 63) * 4;
            bf4 v0 = *(const bf4*)&buf[p ^ 1][m][hb];
            *(bf4*)(H1 + ((size_t)tt * 256 + g * 16 + m) * H_ + hb) = v0;
        }
        p ^= 1;
    }
    {
        const int m = tid >> 6, hb = (tid & 63) * 4;
        *(bf4*)(h1state + (size_t)(g * 16 + m) * H_ + hb) =
            *(const bf4*)&buf[p][m][hb];
    }
}

// ---------------------------------------------------------------------------
// h2 role: blocks 16-31. Chunk ch. 16 waves, ONE n-chain each.
// Nominal VGPRs: u2f 32 + g2f 32 + h2af 32 + h2p/up 8 + w2cc/g1cc 8 + acc 4
// + misc ~10 = ~126 <= 128 -> zero weight remat. W2c/G1c loaded at step top
// (L2/L3-resident workspace); W2c added AFTER the U2 chain so its load has
// full-chain cover. Single raw barrier per step.
// ---------------------------------------------------------------------------
__device__ void h2_role(
    const u16* __restrict__ U2, const u16* __restrict__ gw,
    const float* __restrict__ W2c, const float* __restrict__ G1c,
    u16* __restrict__ H2, float* __restrict__ h2state,
    float* __restrict__ ustate, int ch, u16 (*buf)[16][H_ + 8])
{
    const int g = blockIdx.x - 16;
    const int tid = threadIdx.x;
    const int w = tid >> 6, lane = tid & 63;
    const int col = lane & 15, quad = lane >> 4;
    const int n = w * 16 + col;

    bf8 u2f[8], g2f[8];
#pragma unroll
    for (int kt = 0; kt < 8; ++kt) {
        u2f[kt] = *(const bf8*)(U2 + (size_t)n * H_ + kt * 32 + quad * 8);
        g2f[kt] = *(const bf8*)(gw + (size_t)n * (2 * H_) + H_ + kt * 32 + quad * 8);
    }

    f32x4 h2p, up;
    if (ch == 0) {
        h2p[0]=0.f; h2p[1]=0.f; h2p[2]=0.f; h2p[3]=0.f;
        up[0]=1.f;  up[1]=1.f;  up[2]=1.f;  up[3]=1.f;
    } else {
        size_t idx = (((size_t)g * 16 + w) * 64 + lane) * 4;
        h2p = *(const f32x4*)(h2state + idx);
        up  = *(const f32x4*)(ustate + idx);
    }

#pragma unroll
    for (int r = 0; r < 4; ++r) buf[0][quad * 4 + r][n] = f2b(h2p[r]);
    __syncthreads();
    bf8 h2af[8];
#pragma unroll
    for (int kt = 0; kt < 8; ++kt)
        h2af[kt] = *(const bf8*)&buf[0][col][kt * 32 + quad * 8];

    int p = 0;
    for (int tt = 0; tt < Tc_; ++tt) {
        // C-stream loads issued at step top; consumed after the U2 chain /
        // at the gate -> full latency cover.
        f32x4 w2cc = *(const f32x4*)(W2c +
            ((((size_t)g * Tc_ + tt) * 16 + w) * 64 + lane) * 4);
        f32x4 g1cc = *(const f32x4*)(G1c +
            ((((size_t)g * Tc_ + tt) * 16 + w) * 64 + lane) * 4);

        // h2 preact: U2 @ h2_prev accumulated from zero; (W2@h1+biases)
        // added after the chain (gives the w2cc load full-chain cover).
        f32x4 acc1;
        acc1[0]=0.f; acc1[1]=0.f; acc1[2]=0.f; acc1[3]=0.f;
#pragma unroll
        for (int kt = 0; kt < 8; ++kt)
            acc1 = MFMA(h2af[kt], u2f[kt], acc1);

#pragma unroll
        for (int r = 0; r < 4; ++r) {
            float h2n = fast_tanh(acc1[r] + w2cc[r]);
            h2p[r] = up[r] * h2n + (1.f - up[r]) * h2p[r];
        }
#pragma unroll
        for (int r = 0; r < 4; ++r) buf[p ^ 1][quad * 4 + r][n] = f2b(h2p[r]);
        lds_barrier();
#pragma unroll
        for (int kt = 0; kt < 8; ++kt)
            h2af[kt] = *(const bf8*)&buf[p ^ 1][col][kt * 32 + quad * 8];
        {
            const int m = tid >> 6, hb = (tid & 63) * 4;
            bf4 v0 = *(const bf4*)&buf[p ^ 1][m][hb];
            *(bf4*)(H2 + ((size_t)tt * 256 + g * 16 + m) * H_ + hb) = v0;
        }

        // gate: (g1@h1+bias) + g2 @ h2_new
        f32x4 accg = g1cc;
#pragma unroll
        for (int kt = 0; kt < 8; ++kt)
            accg = MFMA(h2af[kt], g2f[kt], accg);
#pragma unroll
        for (int r = 0; r < 4; ++r) up[r] = fast_sigmoid(accg[r]);

        p ^= 1;
    }
    {
        size_t idx = (((size_t)g * 16 + w) * 64 + lane) * 4;
        *(f32x4*)(h2state + idx) = h2p;
        *(f32x4*)(ustate + idx)  = up;
    }
}

// ---------------------------------------------------------------------------
// k_pipe, lag pipeline across dispatches (1024-thread blocks, 16 waves):
//   blocks 0-15 : h1 of chunk c              (c < NC_)
//   blocks 16-31: h2 of chunk c-2            (2 <= c <= NC_+1)
//   blocks 32+  : unit<18: gemm of chunk c-1 (1 <= c <= NC_)   [B-resident]
//                 unit>=18: out-gemm of c-3  (3 <= c <= NC_+2)
// amdgpu_waves_per_eu(4,4): cap assumed occupancy at 4 waves/EU
// (= 1 workgroup/CU) so the RA budget is 128 VGPRs, not the 64 it picked in
// round 4 when targeting 2 workgroups/CU. All roles' nominal demand is
// designed to fit 128 -> weight fragments stay register-resident (the L2
// re-stream of demoted weights was the ~4300 cy/step bandwidth wall).
// ---------------------------------------------------------------------------
__global__ __launch_bounds__(1024)
__attribute__((amdgpu_waves_per_eu(4, 4))) void k_pipe(
    const float* __restrict__ x, const u16* __restrict__ W1,
    const u16* __restrict__ U1, const float* __restrict__ W1b,
    const float* __restrict__ U1b, u16* __restrict__ H1w,
    u16* __restrict__ h1state,
    const u16* __restrict__ U2, const u16* __restrict__ gwgt,
    const float* __restrict__ W2cr, const float* __restrict__ G1cr,
    u16* __restrict__ H2w, float* __restrict__ h2state,
    float* __restrict__ ustate,
    const u16* __restrict__ H1r, const u16* __restrict__ W2,
    const u16* __restrict__ o1w, const u16* __restrict__ o2w,
    const float* __restrict__ W2b, const float* __restrict__ U2b,
    const float* __restrict__ gbias, const float* __restrict__ o1b,
    const float* __restrict__ o2b,
    float* __restrict__ W2cw, float* __restrict__ G1cw, float* __restrict__ O1cw,
    const u16* __restrict__ H2r, const float* __restrict__ O1r,
    float* __restrict__ out, int c)
{
    __shared__ __align__(16) u16 buf[2][16][H_ + 8];
    if (blockIdx.x < 16) {
        if (c < NC_)
            h1_role(x, W1, U1, W1b, U1b, H1w, h1state, c, buf);
    } else if (blockIdx.x < 32) {
        if (c >= 2 && c <= NC_ + 1)
            h2_role(U2, gwgt, W2cr, G1cr, H2w, h2state, ustate, c - 2, buf);
    } else {
        const int gbk = blockIdx.x - 32;
        const int tid = threadIdx.x;
        const int w = tid >> 6, lane = tid & 63;
        const int col = lane & 15, quad = lane >> 4;
        const int Wv = gbk * 16 + w;   // 0..3039
        const int unit = Wv % 20;      // 0-7: W2c, 8-15: G1c, 16-17: O1c, 18-19: out
        const int j = Wv / 20;         // 0..151
        const bool act = (unit < 18) ? (c >= 1 && c <= NC_)
                                     : (c >= 3 && c <= NC_ + 2);
        if (!act) return;

        // B fragments + bias: loaded ONCE per wave, resident across all tasks
        bf8 bfv[2][8];
        float bias[2];
#pragma unroll
        for (int i = 0; i < 2; ++i) {
            const u16* bp; float bs;
            if (unit < 18) {
                const int n = unit * 32 + i * 16 + col;
                if (n < 256)      { bp = W2   + (size_t)n * H_;             bs = W2b[n] + U2b[n]; }
                else if (n < 512) { bp = gwgt + (size_t)(n - 256) * (2*H_); bs = gbias[n - 256]; }
                else              { bp = o1w  + (size_t)(n - 512) * H_;     bs = o1b[n-512] + o2b[n-512]; }
            } else {
                const int n = (unit - 18) * 32 + i * 16 + col;   // 0..63
                bp = o2w + (size_t)n * H_; bs = 0.f;
            }
            bias[i] = bs;
#pragma unroll
            for (int kt = 0; kt < 8; ++kt)
                bfv[i][kt] = *(const bf8*)(bp + kt * 32 + quad * 8);
        }

        const u16* Ar = (unit < 18) ? H1r : H2r;
        const int tb = (c - 3) * Tc_;

        for (int mt = j; mt < 1024; mt += 152) {
            const int mrow = mt * 16;
            f32x4 acc[2];
#pragma unroll
            for (int i = 0; i < 2; ++i) {
                acc[i][0] = bias[i]; acc[i][1] = bias[i];
                acc[i][2] = bias[i]; acc[i][3] = bias[i];
            }
#pragma unroll
            for (int kt = 0; kt < 8; ++kt) {
                bf8 af = *(const bf8*)(Ar + (size_t)(mrow + col) * H_ + kt * 32 + quad * 8);
                acc[0] = MFMA(af, bfv[0][kt], acc[0]);
                acc[1] = MFMA(af, bfv[1][kt], acc[1]);
            }
            const int tt = mt >> 4, gg = mt & 15;
            if (unit < 16) {
#pragma unroll
                for (int i = 0; i < 2; ++i) {
                    const int nt = unit * 2 + i;   // 0..31
                    float* Cb = (nt < 16) ? W2cw : G1cw;
                    const int nn = nt & 15;
                    size_t idx = ((((size_t)gg * Tc_ + tt) * 16 + nn) * 64 + lane) * 4;
                    *(f32x4*)(Cb + idx) = acc[i];
                }
            } else if (unit < 18) {
#pragma unroll
                for (int i = 0; i < 2; ++i) {
                    const int ot = (unit - 16) * 2 + i;   // 0..3
                    size_t idx = ((((size_t)gg * Tc_ + tt) * 4 + ot) * 64 + lane) * 4;
                    *(f32x4*)(O1cw + idx) = acc[i];
                }
            } else {  // out = O1c (o1@h1 + biases) + h2 @ o2^T
#pragma unroll
                for (int i = 0; i < 2; ++i) {
                    const int ot = (unit - 18) * 2 + i;   // 0..3
                    f32x4 o1v = *(const f32x4*)(O1r +
                        ((((size_t)gg * Tc_ + tt) * 4 + ot) * 64 + lane) * 4);
#pragma unroll
                    for (int r = 0; r < 4; ++r)
                        out[((size_t)(gg * 16 + quad * 4 + r) * T_ + (tb + tt)) * D_ +
                            ot * 16 + col] = acc[i][r] + o1v[r];
                }
            }
        }
    }
}

// ---------------------------------------------------------------------------
extern "C" void kernel_launch(void* const* d_in, const int* in_sizes, int n_in,
                              void* d_out, int out_size, void* d_ws, size_t ws_size,
                              hipStream_t stream)
{
    const float* x   = (const float*)d_in[0];
    const float* W1w = (const float*)d_in[1];
    const float* W1b = (const float*)d_in[2];
    const float* U1w = (const float*)d_in[3];
    const float* U1b = (const float*)d_in[4];
    const float* W2w = (const float*)d_in[5];
    const float* W2b = (const float*)d_in[6];
    const float* U2w = (const float*)d_in[7];
    const float* U2b = (const float*)d_in[8];
    const float* o1w = (const float*)d_in[9];
    const float* o1b = (const float*)d_in[10];
    const float* o2w = (const float*)d_in[11];
    const float* o2b = (const float*)d_in[12];
    const float* gw  = (const float*)d_in[13];
    const float* gb  = (const float*)d_in[14];
    float* out = (float*)d_out;
    (void)in_sizes; (void)n_in; (void)out_size; (void)ws_size;

    char* p = (char*)d_ws;
    u16* W1bf = (u16*)p; p += 16384 * 2;
    u16* U1bf = (u16*)p; p += 65536 * 2;
    u16* W2bf = (u16*)p; p += 65536 * 2;
    u16* U2bf = (u16*)p; p += 65536 * 2;
    u16* o1bf = (u16*)p; p += 16384 * 2;
    u16* o2bf = (u16*)p; p += 16384 * 2;
    u16* gbf  = (u16*)p; p += 131072 * 2;
    u16* H1[2]; u16* H2[2]; float* W2c[2]; float* G1c[2]; float* O1c[3];
    for (int pa = 0; pa < 2; ++pa) {
        H1[pa]  = (u16*)p;   p += (size_t)Tc_ * 131072;   // Tc*256*256 bf16
        H2[pa]  = (u16*)p;   p += (size_t)Tc_ * 131072;   // Tc*256*256 bf16
        W2c[pa] = (float*)p; p += (size_t)Tc_ * 262144;   // Tc*256*256 f32
        G1c[pa] = (float*)p; p += (size_t)Tc_ * 262144;
    }
    for (int pa = 0; pa < 3; ++pa) {
        O1c[pa] = (float*)p; p += (size_t)Tc_ * 65536;    // Tc*256*64 f32
    }
    u16* h1s   = (u16*)p;  p += 131072;
    float* h2s = (float*)p; p += 262144;
    float* us  = (float*)p;

    k_conv<<<dim3(128, 7), 256, 0, stream>>>(W1w, U1w, W2w, U2w, o1w, o2w, gw,
                                             W1bf, U1bf, W2bf, U2bf, o1bf, o2bf, gbf);

    // dispatch c = { h1(c), gemm(c-1), h2(c-2), out-gemm(c-3) }
    for (int c = 0; c <= NC_ + 2; ++c) {
        const int pw  = c & 1;                 // h1 writes H1[pw]; h2 writes H2[pw]
        const int pg  = (c + 1) & 1;           // gemm reads H1[pg]; out-gemm reads H2[pg]
        const int ph  = c & 1;                 // h2 reads W2c/G1c[ph]
        const int s_w = ((c - 1) % 3 + 3) % 3; // gemm writes O1c[s_w] (chunk c-1)
        const int s_r = ((c - 3) % 3 + 3) % 3; // out-gemm reads O1c[s_r] (chunk c-3)
        k_pipe<<<32 + GEMMB_, 1024, 0, stream>>>(
            x, W1bf, U1bf, W1b, U1b, H1[pw], h1s,
            U2bf, gbf, W2c[ph], G1c[ph], H2[pw], h2s, us,
            H1[pg], W2bf, o1bf, o2bf, W2b, U2b, gb, o1b, o2b,
            W2c[pg], G1c[pg], O1c[s_w],
            H2[pg], O1c[s_r], out, c);
    }
}

// Round 6
// 1193.558 us; speedup vs baseline: 1.4543x; 1.4543x over previous
//
#include <hip/hip_runtime.h>

typedef unsigned short u16;
using bf8   = __attribute__((ext_vector_type(8))) short;  // 8 bf16 (4 VGPRs)
using bf4   = __attribute__((ext_vector_type(4))) short;  // 4 bf16
using f32x4 = __attribute__((ext_vector_type(4))) float;

#define B_ 256
#define T_ 512
#define D_ 64
#define H_ 256
#define Tc_ 64
#define NC_ (T_ / Tc_)
#define GEMMB_ 192   // gemm role blocks; 32+192=224 <= 256 CUs

#define MFMA(a, b, c) __builtin_amdgcn_mfma_f32_16x16x32_bf16(a, b, c, 0, 0, 0)

static __device__ inline u16 f2b(float f) {
    unsigned int u = __float_as_uint(f);
    unsigned int r = (u + 0x7fffu + ((u >> 16) & 1u)) >> 16;
    return (u16)r;
}
static __device__ inline float fast_tanh(float x) {
    float e = __expf(2.f * x);
    return 1.f - 2.f / (e + 1.f);
}
static __device__ inline float fast_sigmoid(float x) {
    return 1.f / (1.f + __expf(-x));
}
// Raw barrier: waits LDS ops only, leaves global prefetch loads/stores in
// flight (avoids __syncthreads' compiler-emitted vmcnt(0) drain).
static __device__ inline void lds_barrier() {
    asm volatile("s_waitcnt lgkmcnt(0)" ::: "memory");
    __builtin_amdgcn_s_barrier();
    asm volatile("" ::: "memory");
}

// ---------------------------------------------------------------------------
// k_conv: f32 -> bf16 weight conversion pre-pass.
// ---------------------------------------------------------------------------
__global__ __launch_bounds__(256) void k_conv(
    const float* __restrict__ W1w, const float* __restrict__ U1w,
    const float* __restrict__ W2w, const float* __restrict__ U2w,
    const float* __restrict__ o1w, const float* __restrict__ o2w,
    const float* __restrict__ gw,
    u16* W1bf, u16* U1bf, u16* W2bf, u16* U2bf,
    u16* o1bf, u16* o2bf, u16* gbf)
{
    const int a = blockIdx.y;
    const float* src; u16* dst; int n;
    switch (a) {
        case 0: src = W1w; dst = W1bf; n = 16384;  break;
        case 1: src = U1w; dst = U1bf; n = 65536;  break;
        case 2: src = W2w; dst = W2bf; n = 65536;  break;
        case 3: src = U2w; dst = U2bf; n = 65536;  break;
        case 4: src = o1w; dst = o1bf; n = 16384;  break;
        case 5: src = o2w; dst = o2bf; n = 16384;  break;
        default: src = gw; dst = gbf;  n = 131072; break;
    }
    const int i = (blockIdx.x * 256 + threadIdx.x) * 4;
    if (i < n) {
        f32x4 v = *(const f32x4*)(src + i);
        bf4 o;
        o[0] = (short)f2b(v[0]); o[1] = (short)f2b(v[1]);
        o[2] = (short)f2b(v[2]); o[3] = (short)f2b(v[3]);
        *(bf4*)(dst + i) = o;
    }
}

// ---------------------------------------------------------------------------
// h1 role: blocks 0-15. Chunk c. 8 waves, 2 n-chains each.
// Double-buffered LDS h-tile -> single raw barrier per step.
// ---------------------------------------------------------------------------
__device__ void h1_role(
    const float* __restrict__ x, const u16* __restrict__ W1,
    const u16* __restrict__ U1, const float* __restrict__ W1b,
    const float* __restrict__ U1b, u16* __restrict__ H1,
    u16* __restrict__ h1state, int c, u16 (*buf)[16][H_ + 8])
{
    const int g = blockIdx.x;
    const int tid = threadIdx.x;
    const int w = tid >> 6, lane = tid & 63;
    const int col = lane & 15, quad = lane >> 4;
    const int t0 = c * Tc_;

    bf8 u1f[2][8], w1f[2][2];
    float bias[2];
#pragma unroll
    for (int i = 0; i < 2; ++i) {
        const int n = (w * 2 + i) * 16 + col;
#pragma unroll
        for (int kt = 0; kt < 8; ++kt)
            u1f[i][kt] = *(const bf8*)(U1 + (size_t)n * H_ + kt * 32 + quad * 8);
#pragma unroll
        for (int kt = 0; kt < 2; ++kt)
            w1f[i][kt] = *(const bf8*)(W1 + (size_t)n * D_ + kt * 32 + quad * 8);
        bias[i] = W1b[n] + U1b[n];
    }

    if (c == 0) {
        for (int idx = tid; idx < 16 * (H_ + 8); idx += 512)
            ((u16*)buf[0])[idx] = 0;
    } else {
        const int m = tid >> 5, hb = (tid & 31) * 8;
#pragma unroll
        for (int j = 0; j < 8; ++j)
            buf[0][m][hb + j] = h1state[(size_t)(g * 16 + m) * H_ + hb + j];
    }
    __syncthreads();

    const float* xrow = x + (size_t)(g * 16 + col) * T_ * D_ + quad * 8;
    f32x4 xa[4];
    {
        const float* xp = xrow + (size_t)t0 * D_;
        xa[0] = *(const f32x4*)xp;        xa[1] = *(const f32x4*)(xp + 4);
        xa[2] = *(const f32x4*)(xp + 32); xa[3] = *(const f32x4*)(xp + 36);
    }

    int p = 0;
    for (int tt = 0; tt < Tc_; ++tt) {
        const int tn = t0 + (tt + 1 < Tc_ ? tt + 1 : tt);
        f32x4 xan[4];
        {
            const float* xp = xrow + (size_t)tn * D_;
            xan[0] = *(const f32x4*)xp;        xan[1] = *(const f32x4*)(xp + 4);
            xan[2] = *(const f32x4*)(xp + 32); xan[3] = *(const f32x4*)(xp + 36);
        }
        bf8 haf[8];
#pragma unroll
        for (int kt = 0; kt < 8; ++kt)
            haf[kt] = *(const bf8*)&buf[p][col][kt * 32 + quad * 8];

        bf8 xaf[2];
#pragma unroll
        for (int kt = 0; kt < 2; ++kt) {
            bf8 v;
#pragma unroll
            for (int j = 0; j < 4; ++j) {
                v[j]     = (short)f2b(xa[kt * 2][j]);
                v[j + 4] = (short)f2b(xa[kt * 2 + 1][j]);
            }
            xaf[kt] = v;
        }

        f32x4 acc[2];
#pragma unroll
        for (int i = 0; i < 2; ++i) {
            acc[i][0] = bias[i]; acc[i][1] = bias[i];
            acc[i][2] = bias[i]; acc[i][3] = bias[i];
        }
#pragma unroll
        for (int kt = 0; kt < 8; ++kt)
#pragma unroll
            for (int i = 0; i < 2; ++i)
                acc[i] = MFMA(haf[kt], u1f[i][kt], acc[i]);
#pragma unroll
        for (int kt = 0; kt < 2; ++kt)
#pragma unroll
            for (int i = 0; i < 2; ++i)
                acc[i] = MFMA(xaf[kt], w1f[i][kt], acc[i]);

#pragma unroll
        for (int i = 0; i < 2; ++i) {
            const int n = (w * 2 + i) * 16 + col;
#pragma unroll
            for (int r = 0; r < 4; ++r)
                buf[p ^ 1][quad * 4 + r][n] = f2b(fast_tanh(acc[i][r]));
        }
        lds_barrier();
        {
            const int m = tid >> 5, hb = (tid & 31) * 8;
            bf8 v0 = *(const bf8*)&buf[p ^ 1][m][hb];
            *(bf8*)(H1 + ((size_t)tt * 256 + g * 16 + m) * H_ + hb) = v0;
        }
        xa[0] = xan[0]; xa[1] = xan[1]; xa[2] = xan[2]; xa[3] = xan[3];
        p ^= 1;
    }
    {
        const int m = tid >> 5, hb = (tid & 31) * 8;
#pragma unroll
        for (int j = 0; j < 8; ++j)
            h1state[(size_t)(g * 16 + m) * H_ + hb + j] = buf[p][m][hb + j];
    }
}

// ---------------------------------------------------------------------------
// h2 role: blocks 16-31. Chunk ch. 8 waves, 2 n-chains each.
// out-GEMM offloaded (h2 stored to H2 history, consumed next dispatch).
// W2c AND G1c prefetched one step ahead; single raw barrier per step.
// ---------------------------------------------------------------------------
__device__ void h2_role(
    const u16* __restrict__ U2, const u16* __restrict__ gw,
    const float* __restrict__ W2c, const float* __restrict__ G1c,
    u16* __restrict__ H2, float* __restrict__ h2state,
    float* __restrict__ ustate, int ch, u16 (*buf)[16][H_ + 8])
{
    const int g = blockIdx.x - 16;
    const int tid = threadIdx.x;
    const int w = tid >> 6, lane = tid & 63;
    const int col = lane & 15, quad = lane >> 4;

    bf8 u2f[2][8], g2f[2][8];
#pragma unroll
    for (int i = 0; i < 2; ++i) {
        const int n = (w * 2 + i) * 16 + col;
#pragma unroll
        for (int kt = 0; kt < 8; ++kt) {
            u2f[i][kt] = *(const bf8*)(U2 + (size_t)n * H_ + kt * 32 + quad * 8);
            g2f[i][kt] = *(const bf8*)(gw + (size_t)n * (2 * H_) + H_ + kt * 32 + quad * 8);
        }
    }

    f32x4 h2p[2], up[2];
    if (ch == 0) {
#pragma unroll
        for (int i = 0; i < 2; ++i) {
            h2p[i][0]=0.f; h2p[i][1]=0.f; h2p[i][2]=0.f; h2p[i][3]=0.f;
            up[i][0]=1.f;  up[i][1]=1.f;  up[i][2]=1.f;  up[i][3]=1.f;
        }
    } else {
#pragma unroll
        for (int i = 0; i < 2; ++i) {
            size_t idx = (((size_t)g * 16 + (w * 2 + i)) * 64 + lane) * 4;
            h2p[i] = *(const f32x4*)(h2state + idx);
            up[i]  = *(const f32x4*)(ustate + idx);
        }
    }

#pragma unroll
    for (int i = 0; i < 2; ++i) {
        const int n = (w * 2 + i) * 16 + col;
#pragma unroll
        for (int r = 0; r < 4; ++r) buf[0][quad * 4 + r][n] = f2b(h2p[i][r]);
    }
    __syncthreads();
    bf8 h2af[8];
#pragma unroll
    for (int kt = 0; kt < 8; ++kt)
        h2af[kt] = *(const bf8*)&buf[0][col][kt * 32 + quad * 8];

    // step-0 prefetch of both f32 C streams
    f32x4 w2cr[2], g1cr[2];
#pragma unroll
    for (int i = 0; i < 2; ++i) {
        w2cr[i] = *(const f32x4*)(W2c +
            ((((size_t)g * Tc_ + 0) * 16 + (w * 2 + i)) * 64 + lane) * 4);
        g1cr[i] = *(const f32x4*)(G1c +
            ((((size_t)g * Tc_ + 0) * 16 + (w * 2 + i)) * 64 + lane) * 4);
    }

    int p = 0;
    for (int tt = 0; tt < Tc_; ++tt) {
        const int ttn = (tt + 1 < Tc_) ? tt + 1 : tt;
        f32x4 w2cn[2], g1cn[2];
#pragma unroll
        for (int i = 0; i < 2; ++i) {
            w2cn[i] = *(const f32x4*)(W2c +
                ((((size_t)g * Tc_ + ttn) * 16 + (w * 2 + i)) * 64 + lane) * 4);
            g1cn[i] = *(const f32x4*)(G1c +
                ((((size_t)g * Tc_ + ttn) * 16 + (w * 2 + i)) * 64 + lane) * 4);
        }

        // h2 preact: prefetched (W2@h1+biases) + U2 @ h2_prev
        f32x4 acc1[2];
#pragma unroll
        for (int i = 0; i < 2; ++i) acc1[i] = w2cr[i];
#pragma unroll
        for (int kt = 0; kt < 8; ++kt)
#pragma unroll
            for (int i = 0; i < 2; ++i)
                acc1[i] = MFMA(h2af[kt], u2f[i][kt], acc1[i]);

#pragma unroll
        for (int i = 0; i < 2; ++i)
#pragma unroll
            for (int r = 0; r < 4; ++r) {
                float h2n = fast_tanh(acc1[i][r]);
                h2p[i][r] = up[i][r] * h2n + (1.f - up[i][r]) * h2p[i][r];
            }
#pragma unroll
        for (int i = 0; i < 2; ++i) {
            const int n = (w * 2 + i) * 16 + col;
#pragma unroll
            for (int r = 0; r < 4; ++r) buf[p ^ 1][quad * 4 + r][n] = f2b(h2p[i][r]);
        }
        lds_barrier();
#pragma unroll
        for (int kt = 0; kt < 8; ++kt)
            h2af[kt] = *(const bf8*)&buf[p ^ 1][col][kt * 32 + quad * 8];
        {
            const int m = tid >> 5, hb = (tid & 31) * 8;
            bf8 v0 = *(const bf8*)&buf[p ^ 1][m][hb];
            *(bf8*)(H2 + ((size_t)tt * 256 + g * 16 + m) * H_ + hb) = v0;
        }

        // gate: prefetched (g1@h1+bias) + g2 @ h2_new
        f32x4 accg[2];
#pragma unroll
        for (int i = 0; i < 2; ++i) accg[i] = g1cr[i];
#pragma unroll
        for (int kt = 0; kt < 8; ++kt)
#pragma unroll
            for (int i = 0; i < 2; ++i)
                accg[i] = MFMA(h2af[kt], g2f[i][kt], accg[i]);
#pragma unroll
        for (int i = 0; i < 2; ++i)
#pragma unroll
            for (int r = 0; r < 4; ++r) up[i][r] = fast_sigmoid(accg[i][r]);

#pragma unroll
        for (int i = 0; i < 2; ++i) { w2cr[i] = w2cn[i]; g1cr[i] = g1cn[i]; }
        p ^= 1;
    }
#pragma unroll
    for (int i = 0; i < 2; ++i) {
        size_t idx = (((size_t)g * 16 + (w * 2 + i)) * 64 + lane) * 4;
        *(f32x4*)(h2state + idx) = h2p[i];
        *(f32x4*)(ustate + idx)  = up[i];
    }
}

// ---------------------------------------------------------------------------
// k_pipe, lag pipeline across dispatches:
//   blocks 0-15 : h1 of chunk c              (c < NC_)
//   blocks 16-31: h2 of chunk c-2            (2 <= c <= NC_+1)
//   blocks 32+  : ny<9:  gemm of chunk c-1   (1 <= c <= NC_)   [B-resident]
//                 ny==9: out-gemm of c-3     (3 <= c <= NC_+2)
// occpad: 96 KB of static LDS on top of buf (~17 KB) -> >80 KB/WG -> only
// 1 workgroup/CU fits -> backend occupancy target = 2 waves/EU -> VGPR
// budget 256 (attributes proved ineffective in rounds 1-5; LDS capacity is
// a hard constraint the RA must respect). All roles' weight fragments then
// stay register-resident: the L2 re-stream of demoted weights was the
// ~4300 cy/step bandwidth wall.
// ---------------------------------------------------------------------------
__global__ __launch_bounds__(512) void k_pipe(
    const float* __restrict__ x, const u16* __restrict__ W1,
    const u16* __restrict__ U1, const float* __restrict__ W1b,
    const float* __restrict__ U1b, u16* __restrict__ H1w,
    u16* __restrict__ h1state,
    const u16* __restrict__ U2, const u16* __restrict__ gwgt,
    const float* __restrict__ W2cr, const float* __restrict__ G1cr,
    u16* __restrict__ H2w, float* __restrict__ h2state,
    float* __restrict__ ustate,
    const u16* __restrict__ H1r, const u16* __restrict__ W2,
    const u16* __restrict__ o1w, const u16* __restrict__ o2w,
    const float* __restrict__ W2b, const float* __restrict__ U2b,
    const float* __restrict__ gbias, const float* __restrict__ o1b,
    const float* __restrict__ o2b,
    float* __restrict__ W2cw, float* __restrict__ G1cw, float* __restrict__ O1cw,
    const u16* __restrict__ H2r, const float* __restrict__ O1r,
    float* __restrict__ out, int c)
{
    __shared__ __align__(16) u16 buf[2][16][H_ + 8];
    __shared__ u16 occpad[49152];   // 96 KB occupancy limiter (never touched)
    if (c < 0) {                    // runtime-false; keeps occpad allocated
        ((volatile u16*)occpad)[threadIdx.x] = (u16)threadIdx.x;
        return;
    }
    if (blockIdx.x < 16) {
        if (c < NC_)
            h1_role(x, W1, U1, W1b, U1b, H1w, h1state, c, buf);
    } else if (blockIdx.x < 32) {
        if (c >= 2 && c <= NC_ + 1)
            h2_role(U2, gwgt, W2cr, G1cr, H2w, h2state, ustate, c - 2, buf);
    } else {
        const int gbk = blockIdx.x - 32;
        const int tid = threadIdx.x;
        const int w = tid >> 6, lane = tid & 63;
        const int col = lane & 15, quad = lane >> 4;
        const int Wv = gbk * 8 + w;
        const int ny = Wv % 10;       // 0-3: W2c, 4-7: G1c, 8: O1c, 9: out
        const int j  = Wv / 10;       // 0..152 used
        if (j >= 153) return;
        const bool act = (ny < 9) ? (c >= 1 && c <= NC_)
                                  : (c >= 3 && c <= NC_ + 2);
        if (!act) return;

        // B fragments + bias: loaded ONCE per wave, resident across all tasks
        bf8 bfv[4][8];
        float bias[4];
#pragma unroll
        for (int i = 0; i < 4; ++i) {
            const int n = ny * 64 + i * 16 + col;
            const u16* bp; float bs;
            if (n < 256)      { bp = W2   + (size_t)n * H_;             bs = W2b[n] + U2b[n]; }
            else if (n < 512) { bp = gwgt + (size_t)(n - 256) * (2*H_); bs = gbias[n - 256]; }
            else if (n < 576) { bp = o1w  + (size_t)(n - 512) * H_;     bs = o1b[n-512] + o2b[n-512]; }
            else              { bp = o2w  + (size_t)(n - 576) * H_;     bs = 0.f; }
            bias[i] = bs;
#pragma unroll
            for (int kt = 0; kt < 8; ++kt)
                bfv[i][kt] = *(const bf8*)(bp + kt * 32 + quad * 8);
        }

        const u16* Ar = (ny < 9) ? H1r : H2r;
        float* Cb = W2cw; int ntb = 0;
        if (ny < 4)       { Cb = W2cw; ntb = ny * 4; }
        else if (ny < 8)  { Cb = G1cw; ntb = ny * 4 - 16; }
        else if (ny == 8) { Cb = O1cw; ntb = 0; }
        const int tb = (c - 3) * Tc_;

        for (int mt = j; mt < 1024; mt += 153) {
            const int mrow = mt * 16;
            f32x4 acc[4];
#pragma unroll
            for (int i = 0; i < 4; ++i) {
                acc[i][0] = bias[i]; acc[i][1] = bias[i];
                acc[i][2] = bias[i]; acc[i][3] = bias[i];
            }
#pragma unroll
            for (int kt = 0; kt < 8; ++kt) {
                bf8 af = *(const bf8*)(Ar + (size_t)(mrow + col) * H_ + kt * 32 + quad * 8);
#pragma unroll
                for (int i = 0; i < 4; ++i)
                    acc[i] = MFMA(af, bfv[i][kt], acc[i]);
            }
            const int tt = mrow >> 8, gg = (mrow & 255) >> 4;
            if (ny < 8) {
#pragma unroll
                for (int i = 0; i < 4; ++i) {
                    size_t idx = ((((size_t)gg * Tc_ + tt) * 16 + (ntb + i)) * 64 + lane) * 4;
                    *(f32x4*)(Cb + idx) = acc[i];
                }
            } else if (ny == 8) {
#pragma unroll
                for (int i = 0; i < 4; ++i) {
                    size_t idx = ((((size_t)gg * Tc_ + tt) * 4 + i) * 64 + lane) * 4;
                    *(f32x4*)(O1cw + idx) = acc[i];
                }
            } else {  // ny == 9: out = O1c (o1@h1 + biases) + h2 @ o2^T
#pragma unroll
                for (int i = 0; i < 4; ++i) {
                    f32x4 o1v = *(const f32x4*)(O1r +
                        ((((size_t)gg * Tc_ + tt) * 4 + i) * 64 + lane) * 4);
#pragma unroll
                    for (int r = 0; r < 4; ++r)
                        out[((size_t)(gg * 16 + quad * 4 + r) * T_ + (tb + tt)) * D_ +
                            i * 16 + col] = acc[i][r] + o1v[r];
                }
            }
        }
    }
}

// ---------------------------------------------------------------------------
extern "C" void kernel_launch(void* const* d_in, const int* in_sizes, int n_in,
                              void* d_out, int out_size, void* d_ws, size_t ws_size,
                              hipStream_t stream)
{
    const float* x   = (const float*)d_in[0];
    const float* W1w = (const float*)d_in[1];
    const float* W1b = (const float*)d_in[2];
    const float* U1w = (const float*)d_in[3];
    const float* U1b = (const float*)d_in[4];
    const float* W2w = (const float*)d_in[5];
    const float* W2b = (const float*)d_in[6];
    const float* U2w = (const float*)d_in[7];
    const float* U2b = (const float*)d_in[8];
    const float* o1w = (const float*)d_in[9];
    const float* o1b = (const float*)d_in[10];
    const float* o2w = (const float*)d_in[11];
    const float* o2b = (const float*)d_in[12];
    const float* gw  = (const float*)d_in[13];
    const float* gb  = (const float*)d_in[14];
    float* out = (float*)d_out;
    (void)in_sizes; (void)n_in; (void)out_size; (void)ws_size;

    char* p = (char*)d_ws;
    u16* W1bf = (u16*)p; p += 16384 * 2;
    u16* U1bf = (u16*)p; p += 65536 * 2;
    u16* W2bf = (u16*)p; p += 65536 * 2;
    u16* U2bf = (u16*)p; p += 65536 * 2;
    u16* o1bf = (u16*)p; p += 16384 * 2;
    u16* o2bf = (u16*)p; p += 16384 * 2;
    u16* gbf  = (u16*)p; p += 131072 * 2;
    u16* H1[2]; u16* H2[2]; float* W2c[2]; float* G1c[2]; float* O1c[3];
    for (int pa = 0; pa < 2; ++pa) {
        H1[pa]  = (u16*)p;   p += (size_t)Tc_ * 131072;   // Tc*256*256 bf16
        H2[pa]  = (u16*)p;   p += (size_t)Tc_ * 131072;   // Tc*256*256 bf16
        W2c[pa] = (float*)p; p += (size_t)Tc_ * 262144;   // Tc*256*256 f32
        G1c[pa] = (float*)p; p += (size_t)Tc_ * 262144;
    }
    for (int pa = 0; pa < 3; ++pa) {
        O1c[pa] = (float*)p; p += (size_t)Tc_ * 65536;    // Tc*256*64 f32
    }
    u16* h1s   = (u16*)p;  p += 131072;
    float* h2s = (float*)p; p += 262144;
    float* us  = (float*)p;

    k_conv<<<dim3(128, 7), 256, 0, stream>>>(W1w, U1w, W2w, U2w, o1w, o2w, gw,
                                             W1bf, U1bf, W2bf, U2bf, o1bf, o2bf, gbf);

    // dispatch c = { h1(c), gemm(c-1), h2(c-2), out-gemm(c-3) }
    for (int c = 0; c <= NC_ + 2; ++c) {
        const int pw  = c & 1;                 // h1 writes H1[pw]; h2 writes H2[pw]
        const int pg  = (c + 1) & 1;           // gemm reads H1[pg]; out-gemm reads H2[pg]
        const int ph  = c & 1;                 // h2 reads W2c/G1c[ph]
        const int s_w = ((c - 1) % 3 + 3) % 3; // gemm writes O1c[s_w] (chunk c-1)
        const int s_r = ((c - 3) % 3 + 3) % 3; // out-gemm reads O1c[s_r] (chunk c-3)
        k_pipe<<<32 + GEMMB_, 512, 0, stream>>>(
            x, W1bf, U1bf, W1b, U1b, H1[pw], h1s,
            U2bf, gbf, W2c[ph], G1c[ph], H2[pw], h2s, us,
            H1[pg], W2bf, o1bf, o2bf, W2b, U2b, gb, o1b, o2b,
            W2c[pg], G1c[pg], O1c[s_w],
            H2[pg], O1c[s_r], out, c);
    }
}